// Round 5
// baseline (475.156 us; speedup 1.0000x reference)
//
#include <hip/hip_runtime.h>

#define N_NODES 100000
#define N_EDGES 1600000
#define D 64
#define CAP 64        // slot cap per node; Poisson(16) deg, P(>64) astronomically small
#define OVF_CAP 8192  // overflow edge list capacity (practically unused)
#define N_TILES 1563  // (N_NODES + 63) / 64

// ws layout (bytes):
//   cnt      @ 0          : N_NODES int          (0.4 MB)
//   slots    @ 401408     : N_NODES*CAP int      (25.6 MB)  256B-aligned rows
//   acc      @ 26001408   : N_NODES*D float      (25.6 MB)
//   ovf_cnt  @ 51601408   : int
//   ovf      @ 51601424   : OVF_CAP int2
//   partials @ 51667200   : N_TILES*64 float     (0.4 MB)
#define WS_SLOTS_OFF  401408
#define WS_ACC_OFF    26001408
#define WS_OVFC_OFF   51601408
#define WS_OVF_OFF    51601424
#define WS_PART_OFF   51667200
#define WS_NEEDED     (WS_PART_OFF + N_TILES * 64 * 4)

// ---------------------------------------------------------------------------
// Build capped CSR. R5: 8 edges/thread (was 1) — the R4 counters showed
// VALUBusy 0.34% with one dependent load->atomic->store chain per thread;
// 8 independent chains overlap the ~500cyc atomic round-trips. Edge loads
// via int4 pairs (16B/lane, coalesced).
// ---------------------------------------------------------------------------
__global__ __launch_bounds__(256) void fill_kernel(
    const int* __restrict__ edge_src, const int* __restrict__ edge_dst,
    int* __restrict__ cnt, int* __restrict__ slots,
    int* __restrict__ ovf_cnt, int2* __restrict__ ovf) {
    const int t = blockIdx.x * 256 + threadIdx.x;
    if (t >= N_EDGES / 8) return;  // 200000 threads * 8 = 1.6M edges exactly
    const int4* src4 = (const int4*)(edge_src + t * 8);
    const int4* dst4 = (const int4*)(edge_dst + t * 8);
    int4 s0 = src4[0], s1 = src4[1];
    int4 d0 = dst4[0], d1 = dst4[1];
    int ss[8] = {s0.x, s0.y, s0.z, s0.w, s1.x, s1.y, s1.z, s1.w};
    int dd[8] = {d0.x, d0.y, d0.z, d0.w, d1.x, d1.y, d1.z, d1.w};
    int pos[8];
#pragma unroll
    for (int i = 0; i < 8; ++i) pos[i] = atomicAdd(&cnt[dd[i]], 1);
#pragma unroll
    for (int i = 0; i < 8; ++i) {
        if (pos[i] < CAP) {
            slots[dd[i] * CAP + pos[i]] = ss[i];
        } else {
            int j = atomicAdd(ovf_cnt, 1);
            if (j < OVF_CAP) ovf[j] = make_int2(ss[i], dd[i]);
        }
    }
}

// ---------------------------------------------------------------------------
// Atomic-free gather, float4-vectorized. One wave per node. Lane = (q, c4):
// q = lane>>4 picks slot e+q, c4 = lane&15 picks float4 column group.
// One VMEM instruction fetches FOUR emb rows (4 x 256B); deg~16 -> ~4 wide
// loads instead of 16 scalar. Butterfly over q combines; lanes q==0 store
// the full 256B acc row (16 lanes x 16B, coalesced).
// ---------------------------------------------------------------------------
__global__ __launch_bounds__(256) void gather_kernel(
    const float* __restrict__ emb, const int* __restrict__ cnt,
    const int* __restrict__ slots, float* __restrict__ acc) {
    const int lane = threadIdx.x & 63;
    const int wave = threadIdx.x >> 6;
    const int v = blockIdx.x * 4 + wave;  // grid = N_NODES/4 exactly
    const int q  = lane >> 4;
    const int c4 = lane & 15;
    int deg = cnt[v];
    if (deg > CAP) deg = CAP;
    const int si = slots[v * CAP + lane];  // coalesced full-row read
    const float4* emb4 = (const float4*)emb;

    float4 sum = make_float4(0.f, 0.f, 0.f, 0.f);
    for (int e = 0; e < deg; e += 4) {
        const int idx = e + q;
        const int s = __shfl(si, idx & 63);
        if (idx < deg) {
            float4 a = emb4[s * 16 + c4];
            sum.x += a.x; sum.y += a.y; sum.z += a.z; sum.w += a.w;
        }
    }
    // Combine the 4 q-groups: butterfly over lane bits 4..5 (xor 16, 32).
#pragma unroll
    for (int off = 16; off < 64; off <<= 1) {
        sum.x += __shfl_xor(sum.x, off);
        sum.y += __shfl_xor(sum.y, off);
        sum.z += __shfl_xor(sum.z, off);
        sum.w += __shfl_xor(sum.w, off);
    }
    if (q == 0) {
        ((float4*)acc)[v * 16 + c4] = sum;
    }
}

// Overflow edges (normally zero). R5: parallel grid-stride (the R3 serial
// loop would cost ~0.4us/edge if overflow ever fired). One wave per edge.
__global__ __launch_bounds__(256) void ovf_kernel(
    const float* __restrict__ emb, const int* __restrict__ ovf_cnt,
    const int2* __restrict__ ovf, float* __restrict__ acc) {
    int n = *ovf_cnt;
    if (n > OVF_CAP) n = OVF_CAP;
    const int lane = threadIdx.x & 63;
    const int wv = (blockIdx.x * 256 + threadIdx.x) >> 6;
    const int nwaves = (gridDim.x * 256) >> 6;
    for (int i = wv; i < n; i += nwaves) {
        int2 e = ovf[i];
        unsafeAtomicAdd(&acc[e.y * D + lane], emb[e.x * D + lane]);
    }
}

// ---------------------------------------------------------------------------
// Fallback scatter (only if ws_size < WS_NEEDED): one wave per edge, 64 f32
// hardware atomics into acc. (Round-1 path.)
// ---------------------------------------------------------------------------
__global__ __launch_bounds__(256) void scatter_kernel(
    const float* __restrict__ emb,
    const int* __restrict__ edge_src, const int* __restrict__ edge_dst,
    float* __restrict__ acc) {
    int gid = blockIdx.x * 256 + threadIdx.x;
    int e = gid >> 6;
    int c = gid & 63;
    int s = edge_src[e];
    int d = edge_dst[e];
    unsafeAtomicAdd(&acc[d * D + c], emb[s * D + c]);
}

// ---------------------------------------------------------------------------
// Final pass. Per 64-node tile: z = feat@W1^T + nbr@W2^T; relu(z+b); column
// sums -> per-block partials (plain stores; the R1/R3 atomic epilogue into
// out[64] cost ~650us of L2 same-line serialization). reduce_kernel sums.
// ---------------------------------------------------------------------------
__global__ __launch_bounds__(256) void final_kernel(
    const float* __restrict__ feat, const float* __restrict__ acc,
    const float* __restrict__ W1, const float* __restrict__ b1,
    const float* __restrict__ W2, const float* __restrict__ b2,
    float* __restrict__ partials) {
    __shared__ float ft[64][65];   // [k][node]
    __shared__ float nt[64][65];
    __shared__ float w1s[64 * 64]; // [o][k], read via uniform float4
    __shared__ float w2s[64 * 64];

    const int tid  = threadIdx.x;
    const int lane = tid & 63;
    const int wave = tid >> 6;
    const int ob   = wave * 16;  // this wave's output-column base
    const int node0 = blockIdx.x * 64;

    // Stage W1/W2: 64*64 floats = 1024 float4 each; 4 per thread, coalesced.
    {
        const float4* W1v = (const float4*)W1;
        const float4* W2v = (const float4*)W2;
        float4* w1v = (float4*)w1s;
        float4* w2v = (float4*)w2s;
#pragma unroll
        for (int i = 0; i < 4; ++i) {
            int idx = tid + i * 256;  // 0..1023
            w1v[idx] = W1v[idx];
            w2v[idx] = W2v[idx];
        }
    }

    // Stage feat/acc tiles, transposed. Within a wave: node fixed, c=lane ->
    // 256B coalesced global reads.
#pragma unroll 4
    for (int it = 0; it < 16; ++it) {
        const int r = wave + it * 4;
        const int node = node0 + r;
        float fv = 0.f, nv = 0.f;
        if (node < N_NODES) {
            fv = feat[node * D + lane];
            nv = acc[node * D + lane];
        }
        ft[lane][r] = fv;
        nt[lane][r] = nv;
    }
    __syncthreads();

    float z[16];
#pragma unroll
    for (int j = 0; j < 16; ++j) z[j] = 0.f;

    for (int k = 0; k < D; k += 4) {
        const float f0 = ft[k + 0][lane];
        const float f1 = ft[k + 1][lane];
        const float f2 = ft[k + 2][lane];
        const float f3 = ft[k + 3][lane];
        const float n0 = nt[k + 0][lane];
        const float n1 = nt[k + 1][lane];
        const float n2 = nt[k + 2][lane];
        const float n3 = nt[k + 3][lane];
#pragma unroll
        for (int j = 0; j < 16; ++j) {
            const float4 w1 = *(const float4*)&w1s[(ob + j) * 64 + k];
            const float4 w2 = *(const float4*)&w2s[(ob + j) * 64 + k];
            z[j] += f0 * w1.x + f1 * w1.y + f2 * w1.z + f3 * w1.w
                  + n0 * w2.x + n1 * w2.y + n2 * w2.z + n3 * w2.w;
        }
    }

    // Bias + ReLU (guard OOB nodes: bias alone can be positive).
    float sums[16];
    const int node = node0 + lane;
#pragma unroll
    for (int j = 0; j < 16; ++j) {
        float u = z[j] + b1[ob + j] + b2[ob + j];
        u = (u > 0.f) ? u : 0.f;
        sums[j] = (node < N_NODES) ? u : 0.f;
    }

    // Reduce across 64 lanes; lane 0 stores the block partial (NO atomics).
#pragma unroll
    for (int j = 0; j < 16; ++j) {
        float v = sums[j];
        for (int off = 32; off > 0; off >>= 1) v += __shfl_down(v, off);
        if (lane == 0) partials[blockIdx.x * 64 + ob + j] = v;
    }
}

// ---------------------------------------------------------------------------
// Sum partials[N_TILES][64] -> out[64]. One block; coalesced; LDS combine.
// ---------------------------------------------------------------------------
__global__ __launch_bounds__(256) void reduce_kernel(
    const float* __restrict__ partials, float* __restrict__ out) {
    __shared__ float red[4][64];
    const int col = threadIdx.x & 63;
    const int seg = threadIdx.x >> 6;
    const int rows_per_seg = (N_TILES + 3) / 4;  // 391
    const int r0 = seg * rows_per_seg;
    int r1 = r0 + rows_per_seg;
    if (r1 > N_TILES) r1 = N_TILES;
    float s = 0.f;
    for (int r = r0; r < r1; ++r) s += partials[r * 64 + col];
    red[seg][col] = s;
    __syncthreads();
    if (seg == 0) {
        out[col] = red[0][col] + red[1][col] + red[2][col] + red[3][col];
    }
}

extern "C" void kernel_launch(void* const* d_in, const int* in_sizes, int n_in,
                              void* d_out, int out_size, void* d_ws, size_t ws_size,
                              hipStream_t stream) {
    const float* feat = (const float*)d_in[0];
    const float* emb  = (const float*)d_in[1];
    const float* W1   = (const float*)d_in[2];
    const float* b1   = (const float*)d_in[3];
    const float* W2   = (const float*)d_in[4];
    const float* b2   = (const float*)d_in[5];
    const int* edge_src = (const int*)d_in[6];
    const int* edge_dst = (const int*)d_in[7];
    float* out = (float*)d_out;
    char* ws = (char*)d_ws;

    if (ws_size >= (size_t)WS_NEEDED) {
        int*   cnt      = (int*)ws;
        int*   slots    = (int*)(ws + WS_SLOTS_OFF);
        float* acc      = (float*)(ws + WS_ACC_OFF);
        int*   ovf_cnt  = (int*)(ws + WS_OVFC_OFF);
        int2*  ovf      = (int2*)(ws + WS_OVF_OFF);
        float* partials = (float*)(ws + WS_PART_OFF);

        hipMemsetAsync(cnt, 0, N_NODES * sizeof(int), stream);
        hipMemsetAsync(ovf_cnt, 0, sizeof(int), stream);

        const int fill_threads = N_EDGES / 8;  // 200000
        fill_kernel<<<(fill_threads + 255) / 256, 256, 0, stream>>>(
            edge_src, edge_dst, cnt, slots, ovf_cnt, ovf);
        gather_kernel<<<N_NODES / 4, 256, 0, stream>>>(emb, cnt, slots, acc);
        ovf_kernel<<<16, 256, 0, stream>>>(emb, ovf_cnt, ovf, acc);

        final_kernel<<<N_TILES, 256, 0, stream>>>(feat, acc, W1, b1, W2, b2,
                                                  partials);
        reduce_kernel<<<1, 256, 0, stream>>>(partials, out);
    } else {
        // Fallback: atomic scatter (R1 path, correct but slow).
        float* acc = (float*)ws;
        hipMemsetAsync(acc, 0, (size_t)N_NODES * D * sizeof(float), stream);
        scatter_kernel<<<(N_EDGES * 64) / 256, 256, 0, stream>>>(emb, edge_src,
                                                                 edge_dst, acc);
        float* partials = (float*)(ws + (size_t)N_NODES * D * sizeof(float));
        final_kernel<<<N_TILES, 256, 0, stream>>>(feat, acc, W1, b1, W2, b2,
                                                  partials);
        reduce_kernel<<<1, 256, 0, stream>>>(partials, out);
    }
}